// Round 1
// 57.847 us; speedup vs baseline: 1.0949x; 1.0949x over previous
//
#include <hip/hip_runtime.h>
#include <math.h>

// QuantumLayer B=512, Q=14 — closed-form transfer-matrix contraction.
//
// The circuit [RY(x)·RY(w0) layer] -> CNOT chain -> [RY(w1) layer] -> CNOT
// chain -> <Z_i> is a bond-dim-2 tensor network:
//   * chain #2 folds into measurement: C^T Z_i C = Z_0...Z_i (prefix parity)
//   * chain #1 on the product state gives chi(b) = prod_j u_j(b_j ^ b_{j-1}),
//     u_j = (cos a_j, sin a_j), a_j = (x_j + w0_j)/2   [the g = m^(m>>1) fact]
//   * RY(w1_j) pushed into the observable: M_j = cos(w1_j) Z - sin(w1_j) X
// Then out_i = <chi| M_0 x...x M_i x I |chi> contracts left-to-right with a
// symmetric 2x2 bra-ket bond F_j = M_j . (U_j F_{j-1} U_j^T), U_j=[[c,s],[s,c]],
// and the identity suffix collapses (cos^2+sin^2=1) to
//   out_i = F00 + F11 + 2*sin(2a_{i+1})*F01      (i<13; last: G==1).
//
// One thread per batch row: 28 sincosf + 14 recursion steps. Replaces the
// 2^14-amplitude statevector simulation (~24us) with ~200 FLOPs/row (~3us,
// launch-latency bound). Remaining dur_us floor is the harness's 256MiB
// workspace fill (~39.5us at 85% HBM peak).

#define Q 14

__global__ __launch_bounds__(64)
void quantum_kernel(const float* __restrict__ x,   // [B,14]
                    const float* __restrict__ w,   // [2,14]
                    float* __restrict__ out,       // [B,14]
                    int B)
{
    const int b = blockIdx.x * 64 + threadIdx.x;
    if (b >= B) return;

    float ca[Q], sa[Q], s2a[Q], cw[Q], sw[Q];
#pragma unroll
    for (int j = 0; j < Q; ++j) {
        // merged RY(x)·RY(w0): same-wire RYs compose, half-angle a_j
        float alpha = 0.5f * (x[b * Q + j] + w[j]);
        float s, c;
        sincosf(alpha, &s, &c);
        ca[j] = c;
        sa[j] = s;
        s2a[j] = 2.0f * c * s;            // sin(x_j + w0_j)
        sincosf(w[Q + j], &sw[j], &cw[j]); // full angle w1_j for M_j
    }

    // F = [[f00, f01],[f01, f11]] (symmetric). Init = |0><0| bond (b_{-1}=0).
    float f00 = 1.0f, f11 = 0.0f, f01 = 0.0f;
#pragma unroll
    for (int j = 0; j < Q; ++j) {
        const float c = ca[j], s = sa[j];
        const float cc = c * c, ss = s * s, cs = c * s;
        const float cross = 2.0f * cs * f01;
        const float h00 = cc * f00 + cross + ss * f11;   // U F U^T
        const float h11 = ss * f00 + cross + cc * f11;
        const float h01 = cs * (f00 + f11) + f01;
        f00 = cw[j] * h00;                                // elementwise * M_j
        f11 = -cw[j] * h11;
        f01 = -sw[j] * h01;
        const float g = (j < Q - 1) ? s2a[j + 1] : 1.0f;  // suffix environment
        out[b * Q + j] = f00 + f11 + 2.0f * g * f01;
    }
}

extern "C" void kernel_launch(void* const* d_in, const int* in_sizes, int n_in,
                              void* d_out, int out_size, void* d_ws, size_t ws_size,
                              hipStream_t stream) {
    const float* x = (const float*)d_in[0];
    const float* w = (const float*)d_in[1];
    float* out = (float*)d_out;
    const int B = in_sizes[0] / Q;   // 512
    const int grid = (B + 63) / 64;
    quantum_kernel<<<dim3(grid), dim3(64), 0, stream>>>(x, w, out, B);
}

// Round 2
// 55.490 us; speedup vs baseline: 1.1414x; 1.0425x over previous
//
#include <hip/hip_runtime.h>
#include <math.h>

// QuantumLayer B=512, Q=14 — closed-form transfer-matrix contraction,
// trig parallelized across (row, j).
//
// Math (unchanged from prev round, verified):
//   * CNOT chain #2 folds into measurement: C^T Z_i C = Z_0...Z_i
//   * chain #1 on the product state: chi(b) = prod_j u_j(b_j ^ b_{j-1}),
//     u_j = (cos a_j, sin a_j), a_j = (x_j + w0_j)/2
//   * RY(w1_j) pushed into the observable: M_j = cos(w1_j) Z - sin(w1_j) X
//   * out_i = F00 + F11 + 2*sin(x_{i+1}+w0_{i+1})*F01, with symmetric 2x2
//     bond F_j = M_j . (U_j F_{j-1} U_j^T); identity suffix collapses to
//     the single off-diagonal factor (prob. conservation).
//
// Perf structure: previous round ran 512 threads total (8 CUs, 1 wave/SIMD)
// with 28 serial libm sincosf each -> latency-bound ~7us. Now: one sincosf
// per thread over 7168 (row,j) items staged to LDS; 16 threads/block then run
// the 14-step recursion (dep chain ~400 cyc, negligible). 32 blocks x 256.
// Remaining dur_us floor: harness 256MiB workspace fill (39.3us @85% HBM)
// + reset-dispatch overhead.

#define Q 14
#define ROWS 16                  // batch rows per block
#define BLOCK 256                // >= ROWS*Q = 224

__global__ __launch_bounds__(BLOCK)
void quantum_kernel(const float* __restrict__ x,   // [B,14]
                    const float* __restrict__ w,   // [2,14]
                    float* __restrict__ out,       // [B,14]
                    int B)
{
    __shared__ float2 csA[ROWS][Q];   // (cos a, sin a) per (row, j)
    __shared__ float  s2A[ROWS][Q];   // sin(x_j + w0_j) = 2 c s
    __shared__ float2 csW[Q];         // (cos w1_j, sin w1_j), batch-uniform

    const int t = threadIdx.x;
    const int rowBase = blockIdx.x * ROWS;

    if (t < ROWS * Q) {
        const int r = t / Q;          // const-div -> magic mul
        const int j = t - r * Q;
        const int b = rowBase + r;
        if (b < B) {
            // merged RY(x)·RY(w0): same-wire RYs compose, half-angle
            const float alpha = 0.5f * (x[b * Q + j] + w[j]);
            float s, c;
            sincosf(alpha, &s, &c);
            csA[r][j] = make_float2(c, s);
            s2A[r][j] = 2.0f * c * s;
        }
        if (r == 0) {
            float sw_, cw_;
            sincosf(w[Q + j], &sw_, &cw_);
            csW[j] = make_float2(cw_, sw_);
        }
    }
    __syncthreads();

    if (t < ROWS) {
        const int b = rowBase + t;
        if (b < B) {
            // F = [[f00, f01],[f01, f11]] symmetric; init |0><0| bond.
            float f00 = 1.0f, f11 = 0.0f, f01 = 0.0f;
            float outv[Q];
#pragma unroll
            for (int j = 0; j < Q; ++j) {
                const float2 cs = csA[t][j];
                const float c = cs.x, s = cs.y;
                const float cc = c * c, ss = s * s, csx = c * s;
                const float cross = 2.0f * csx * f01;
                const float h00 = cc * f00 + cross + ss * f11;   // U F U^T
                const float h11 = ss * f00 + cross + cc * f11;
                const float h01 = csx * (f00 + f11) + f01;
                const float2 wv = csW[j];
                f00 =  wv.x * h00;                               // * M_j
                f11 = -wv.x * h11;
                f01 = -wv.y * h01;
                const float g = (j < Q - 1) ? s2A[t][j + 1] : 1.0f;
                outv[j] = f00 + f11 + 2.0f * g * f01;
            }
#pragma unroll
            for (int j = 0; j < Q; ++j) out[b * Q + j] = outv[j];
        }
    }
}

extern "C" void kernel_launch(void* const* d_in, const int* in_sizes, int n_in,
                              void* d_out, int out_size, void* d_ws, size_t ws_size,
                              hipStream_t stream) {
    const float* x = (const float*)d_in[0];
    const float* w = (const float*)d_in[1];
    float* out = (float*)d_out;
    const int B = in_sizes[0] / Q;   // 512
    const int grid = (B + ROWS - 1) / ROWS;
    quantum_kernel<<<dim3(grid), dim3(BLOCK), 0, stream>>>(x, w, out, B);
}